// Round 1
// baseline (3003.625 us; speedup 1.0000x reference)
//
#include <hip/hip_runtime.h>

// SAGEConv mean aggregator, bias=False, fp32.
//   neigh[v] = sum_{(u->v)} h[u];  deg[v] = in-degree
//   out = h @ W_self + (neigh/max(deg,1)) @ W_neigh
// Inputs: h[100000*128] f32, src[1.6M] i32, dst[1.6M] i32,
//         W_self[128*128] f32, W_neigh[128*128] f32. Output f32 [100000*128].

constexpr int NN = 100000;
constexpr int NE = 1600000;
constexpr int D  = 128;

// ---------------------------------------------------------------------------
// Phase 1: edge scatter. 32 lanes per edge, each lane handles one float4
// (4 cols). Row gather is a fully-coalesced 512B read; scatter-add via
// hardware fp32 atomics (agent scope, relaxed -> global_atomic_add_f32,
// fire-and-forget).
// ---------------------------------------------------------------------------
__global__ __launch_bounds__(256) void sage_scatter(
    const float* __restrict__ h, const int* __restrict__ src,
    const int* __restrict__ dst, float* __restrict__ neigh,
    float* __restrict__ deg)
{
    long long g = (long long)blockIdx.x * 256 + threadIdx.x;
    int e    = (int)(g >> 5);
    int lane = (int)(g & 31);
    if (e >= NE) return;
    int s = src[e];
    int d = dst[e];
    float4 v = ((const float4*)(h + (size_t)s * D))[lane];
    float* np = neigh + (size_t)d * D + lane * 4;
    __hip_atomic_fetch_add(np + 0, v.x, __ATOMIC_RELAXED, __HIP_MEMORY_SCOPE_AGENT);
    __hip_atomic_fetch_add(np + 1, v.y, __ATOMIC_RELAXED, __HIP_MEMORY_SCOPE_AGENT);
    __hip_atomic_fetch_add(np + 2, v.z, __ATOMIC_RELAXED, __HIP_MEMORY_SCOPE_AGENT);
    __hip_atomic_fetch_add(np + 3, v.w, __ATOMIC_RELAXED, __HIP_MEMORY_SCOPE_AGENT);
    if (lane == 0)
        __hip_atomic_fetch_add(deg + d, 1.0f, __ATOMIC_RELAXED, __HIP_MEMORY_SCOPE_AGENT);
}

// ---------------------------------------------------------------------------
// Phase 2: out = X @ Wcat, X = [h | neigh/max(deg,1)] (100000 x 256),
// Wcat = [W_self ; W_neigh] (256 x 128).
// Block = 256 threads, 32 nodes/block. Xs swizzled (col ^ (n&7)<<2) to avoid
// 4-way bank conflicts on the per-k broadcast reads. Wcat staged to LDS in
// four 64-row chunks. Register tile: 2 nodes x 8 cols per thread
// (cols tc*4..+3 and 64+tc*4..+3 -> 2-way-max LDS reads, coalesced stores).
// LDS: 32*256*4 + 64*128*4 = 64 KiB exactly.
// ---------------------------------------------------------------------------
__global__ __launch_bounds__(256) void sage_gemm(
    const float* __restrict__ h, const float* __restrict__ neigh,
    const float* __restrict__ deg, const float* __restrict__ Wself,
    const float* __restrict__ Wneigh, float* __restrict__ out)
{
    __shared__ float Xs[32][256];
    __shared__ float Ws[64 * 128];

    const int t  = threadIdx.x;
    const int v0 = blockIdx.x * 32;

    // ---- load Xs: 32 nodes x 64 float4 = 2048 float4, 8 per thread ----
#pragma unroll
    for (int i = 0; i < 8; ++i) {
        int f  = t + i * 256;      // 0..2047
        int n  = f >> 6;           // node-in-block 0..31
        int c4 = f & 63;           // float4 col 0..63
        int v  = v0 + n;
        float4 val;
        if (c4 < 32) {
            val = ((const float4*)(h + (size_t)v * D))[c4];
        } else {
            float inv = 1.0f / fmaxf(deg[v], 1.0f);
            float4 s  = ((const float4*)(neigh + (size_t)v * D))[c4 - 32];
            val = make_float4(s.x * inv, s.y * inv, s.z * inv, s.w * inv);
        }
        int colbase = (c4 * 4) ^ ((n & 7) << 2);   // 4-aligned XOR swizzle
        *((float4*)&Xs[n][colbase]) = val;
    }

    const int tc = t & 15;     // col group 0..15
    const int nq = t >> 4;     // 0..15
    const int n0 = nq, n1 = nq + 16;
    const int sw0 = (n0 & 7) << 2;
    const int sw1 = (n1 & 7) << 2;

    float4 aA0 = {0,0,0,0}, aB0 = {0,0,0,0};
    float4 aA1 = {0,0,0,0}, aB1 = {0,0,0,0};

    for (int chunk = 0; chunk < 4; ++chunk) {
        __syncthreads();   // Xs ready (chunk 0) / previous Ws reads done
        // ---- stage Wcat rows [chunk*64, chunk*64+64) : 2048 float4 ----
#pragma unroll
        for (int i = 0; i < 8; ++i) {
            int f  = t + i * 256;
            int kk = f >> 5;       // 0..63
            int c4 = f & 31;       // float4 col 0..31
            int gk = chunk * 64 + kk;
            const float* Wp = (gk < 128) ? (Wself + (size_t)gk * D)
                                         : (Wneigh + (size_t)(gk - 128) * D);
            ((float4*)Ws)[kk * 32 + c4] = ((const float4*)Wp)[c4];
        }
        __syncthreads();

#pragma unroll 8
        for (int kk = 0; kk < 64; ++kk) {
            int k = chunk * 64 + kk;
            float x0 = Xs[n0][k ^ sw0];
            float x1 = Xs[n1][k ^ sw1];
            float4 wA = ((const float4*)Ws)[kk * 32 + tc];        // cols tc*4
            float4 wB = ((const float4*)Ws)[kk * 32 + 16 + tc];   // cols 64+tc*4
            aA0.x += x0 * wA.x; aA0.y += x0 * wA.y; aA0.z += x0 * wA.z; aA0.w += x0 * wA.w;
            aB0.x += x0 * wB.x; aB0.y += x0 * wB.y; aB0.z += x0 * wB.z; aB0.w += x0 * wB.w;
            aA1.x += x1 * wA.x; aA1.y += x1 * wA.y; aA1.z += x1 * wA.z; aA1.w += x1 * wA.w;
            aB1.x += x1 * wB.x; aB1.y += x1 * wB.y; aB1.z += x1 * wB.z; aB1.w += x1 * wB.w;
        }
    }

    float4* o0 = (float4*)(out + (size_t)(v0 + n0) * D);
    o0[tc]      = aA0;
    o0[16 + tc] = aB0;
    float4* o1 = (float4*)(out + (size_t)(v0 + n1) * D);
    o1[tc]      = aA1;
    o1[16 + tc] = aB1;
}

extern "C" void kernel_launch(void* const* d_in, const int* in_sizes, int n_in,
                              void* d_out, int out_size, void* d_ws, size_t ws_size,
                              hipStream_t stream) {
    const float* h      = (const float*)d_in[0];
    const int*   src    = (const int*)d_in[1];
    const int*   dst    = (const int*)d_in[2];
    const float* Wself  = (const float*)d_in[3];
    const float* Wneigh = (const float*)d_in[4];
    float*       out    = (float*)d_out;

    float* neigh = (float*)d_ws;                       // NN*D floats
    float* deg   = neigh + (size_t)NN * D;             // NN floats

    size_t zero_bytes = ((size_t)NN * D + NN) * sizeof(float);
    hipMemsetAsync(d_ws, 0, zero_bytes, stream);

    // scatter: 32 threads per edge -> NE*32 threads / 256 = 200000 blocks
    dim3 sgrid((unsigned)(((size_t)NE * 32 + 255) / 256));
    sage_scatter<<<sgrid, 256, 0, stream>>>(h, src, dst, neigh, deg);

    // gemm: 32 nodes per block -> 3125 blocks
    dim3 ggrid(NN / 32);
    sage_gemm<<<ggrid, 256, 0, stream>>>(h, neigh, deg, Wself, Wneigh, out);
}

// Round 2
// 518.600 us; speedup vs baseline: 5.7918x; 5.7918x over previous
//
#include <hip/hip_runtime.h>

// SAGEConv mean aggregator, fp32, CSR-pull version.
//   R1 post-mortem: atomic scatter = 2760us (92% of total), 3.3GB atomic
//   write traffic at 1.1% VALUBusy. Replaced with device-built CSR + pull.
// Phases: count(dst) -> scan -> fill(eidx) -> pull(mean) -> gemm.

constexpr int NN = 100000;
constexpr int NE = 1600000;
constexpr int D  = 128;
constexpr int TILE = 1024;                     // scan tile (256 thr x 4)
constexpr int N_TILES = (NN + TILE - 1) / TILE; // 98

// ---------------------------------------------------------------------------
// 1) histogram of dst
// ---------------------------------------------------------------------------
__global__ __launch_bounds__(256) void k_count(
    const int* __restrict__ dst, int* __restrict__ count)
{
    int e = blockIdx.x * 256 + threadIdx.x;
    if (e < NE) atomicAdd(&count[dst[e]], 1);
}

// ---------------------------------------------------------------------------
// 2a) per-tile exclusive scan (tile=1024, block=256, 4 elems/thread)
// ---------------------------------------------------------------------------
__global__ __launch_bounds__(256) void k_scan1(
    const int* __restrict__ count, int* __restrict__ offs,
    int* __restrict__ tile_sums)
{
    __shared__ int sdata[256];
    const int t = threadIdx.x, tile = blockIdx.x;
    const int base = tile * TILE + t * 4;
    int c[4];
#pragma unroll
    for (int j = 0; j < 4; ++j)
        c[j] = (base + j < NN) ? count[base + j] : 0;
    int local = c[0] + c[1] + c[2] + c[3];
    sdata[t] = local;
    __syncthreads();
    for (int off = 1; off < 256; off <<= 1) {
        int v = (t >= off) ? sdata[t - off] : 0;
        __syncthreads();
        sdata[t] += v;
        __syncthreads();
    }
    int excl = sdata[t] - local;
    int run = excl;
#pragma unroll
    for (int j = 0; j < 4; ++j) {
        if (base + j < NN) offs[base + j] = run;
        run += c[j];
    }
    if (t == 255) tile_sums[tile] = sdata[255];
}

// 2b) scan the tile sums (single block)
__global__ __launch_bounds__(128) void k_scan2(
    const int* __restrict__ tile_sums, int* __restrict__ tile_base)
{
    __shared__ int sdata[128];
    int t = threadIdx.x;
    int v = (t < N_TILES) ? tile_sums[t] : 0;
    sdata[t] = v;
    __syncthreads();
    for (int off = 1; off < 128; off <<= 1) {
        int x = (t >= off) ? sdata[t - off] : 0;
        __syncthreads();
        sdata[t] += x;
        __syncthreads();
    }
    if (t < N_TILES) tile_base[t] = sdata[t] - v;
}

// 2c) add tile bases; init cursors
__global__ __launch_bounds__(256) void k_scan3(
    int* __restrict__ offs, const int* __restrict__ tile_base,
    int* __restrict__ cursor)
{
    int i = blockIdx.x * 256 + threadIdx.x;
    if (i < NN) {
        int o = offs[i] + tile_base[i / TILE];
        offs[i] = o;
        cursor[i] = o;
    }
}

// ---------------------------------------------------------------------------
// 3) fill edge index: eidx[slot in dst's segment] = src
// ---------------------------------------------------------------------------
__global__ __launch_bounds__(256) void k_fill(
    const int* __restrict__ src, const int* __restrict__ dst,
    int* __restrict__ cursor, int* __restrict__ eidx)
{
    int e = blockIdx.x * 256 + threadIdx.x;
    if (e < NE) {
        int pos = atomicAdd(&cursor[dst[e]], 1);
        eidx[pos] = src[e];
    }
}

// ---------------------------------------------------------------------------
// 4) pull aggregation: one 32-lane group per node, lane owns one float4
//    (4 cols). Each edge = one coalesced 512B row read. Writes the MEAN.
// ---------------------------------------------------------------------------
__global__ __launch_bounds__(256) void k_pull(
    const float* __restrict__ h, const int* __restrict__ offs,
    const int* __restrict__ count, const int* __restrict__ eidx,
    float* __restrict__ neigh)
{
    const int lane  = threadIdx.x & 31;
    const int group = threadIdx.x >> 5;
    const int v = blockIdx.x * 8 + group;
    if (v >= NN) return;
    const int beg = offs[v];
    const int deg = count[v];
    const int end = beg + deg;
    const float4* __restrict__ h4 = (const float4*)h;

    float4 a0 = {0, 0, 0, 0}, a1 = {0, 0, 0, 0};
    int e = beg;
    for (; e + 1 < end; e += 2) {
        int s0 = eidx[e], s1 = eidx[e + 1];
        float4 x0 = h4[(size_t)s0 * 32 + lane];
        float4 x1 = h4[(size_t)s1 * 32 + lane];
        a0.x += x0.x; a0.y += x0.y; a0.z += x0.z; a0.w += x0.w;
        a1.x += x1.x; a1.y += x1.y; a1.z += x1.z; a1.w += x1.w;
    }
    if (e < end) {
        float4 x0 = h4[(size_t)eidx[e] * 32 + lane];
        a0.x += x0.x; a0.y += x0.y; a0.z += x0.z; a0.w += x0.w;
    }
    float inv = (deg > 0) ? 1.0f / (float)deg : 0.0f;
    float4 m = make_float4((a0.x + a1.x) * inv, (a0.y + a1.y) * inv,
                           (a0.z + a1.z) * inv, (a0.w + a1.w) * inv);
    ((float4*)(neigh + (size_t)v * D))[lane] = m;
}

// ---------------------------------------------------------------------------
// 5) out = X @ Wcat, X = [h | neigh_mean] (100000 x 256),
//    Wcat = [W_self ; W_neigh] (256 x 128). Same as R1 (32 nodes/block,
//    swizzled Xs, Ws in 64-row chunks, 2 nodes x 8 cols per thread).
// ---------------------------------------------------------------------------
__global__ __launch_bounds__(256) void sage_gemm(
    const float* __restrict__ h, const float* __restrict__ neigh,
    const float* __restrict__ Wself, const float* __restrict__ Wneigh,
    float* __restrict__ out)
{
    __shared__ float Xs[32][256];
    __shared__ float Ws[64 * 128];

    const int t  = threadIdx.x;
    const int v0 = blockIdx.x * 32;

#pragma unroll
    for (int i = 0; i < 8; ++i) {
        int f  = t + i * 256;
        int n  = f >> 6;
        int c4 = f & 63;
        int v  = v0 + n;
        float4 val = (c4 < 32)
            ? ((const float4*)(h + (size_t)v * D))[c4]
            : ((const float4*)(neigh + (size_t)v * D))[c4 - 32];
        int colbase = (c4 * 4) ^ ((n & 7) << 2);
        *((float4*)&Xs[n][colbase]) = val;
    }

    const int tc = t & 15;
    const int nq = t >> 4;
    const int n0 = nq, n1 = nq + 16;
    const int sw0 = (n0 & 7) << 2;
    const int sw1 = (n1 & 7) << 2;

    float4 aA0 = {0,0,0,0}, aB0 = {0,0,0,0};
    float4 aA1 = {0,0,0,0}, aB1 = {0,0,0,0};

    for (int chunk = 0; chunk < 4; ++chunk) {
        __syncthreads();
#pragma unroll
        for (int i = 0; i < 8; ++i) {
            int f  = t + i * 256;
            int kk = f >> 5;
            int c4 = f & 31;
            int gk = chunk * 64 + kk;
            const float* Wp = (gk < 128) ? (Wself + (size_t)gk * D)
                                         : (Wneigh + (size_t)(gk - 128) * D);
            ((float4*)Ws)[kk * 32 + c4] = ((const float4*)Wp)[c4];
        }
        __syncthreads();

#pragma unroll 8
        for (int kk = 0; kk < 64; ++kk) {
            int k = chunk * 64 + kk;
            float x0 = Xs[n0][k ^ sw0];
            float x1 = Xs[n1][k ^ sw1];
            float4 wA = ((const float4*)Ws)[kk * 32 + tc];
            float4 wB = ((const float4*)Ws)[kk * 32 + 16 + tc];
            aA0.x += x0 * wA.x; aA0.y += x0 * wA.y; aA0.z += x0 * wA.z; aA0.w += x0 * wA.w;
            aB0.x += x0 * wB.x; aB0.y += x0 * wB.y; aB0.z += x0 * wB.z; aB0.w += x0 * wB.w;
            aA1.x += x1 * wA.x; aA1.y += x1 * wA.y; aA1.z += x1 * wA.z; aA1.w += x1 * wA.w;
            aB1.x += x1 * wB.x; aB1.y += x1 * wB.y; aB1.z += x1 * wB.z; aB1.w += x1 * wB.w;
        }
    }

    float4* o0 = (float4*)(out + (size_t)(v0 + n0) * D);
    o0[tc]      = aA0;
    o0[16 + tc] = aB0;
    float4* o1 = (float4*)(out + (size_t)(v0 + n1) * D);
    o1[tc]      = aA1;
    o1[16 + tc] = aB1;
}

extern "C" void kernel_launch(void* const* d_in, const int* in_sizes, int n_in,
                              void* d_out, int out_size, void* d_ws, size_t ws_size,
                              hipStream_t stream) {
    const float* h      = (const float*)d_in[0];
    const int*   src    = (const int*)d_in[1];
    const int*   dst    = (const int*)d_in[2];
    const float* Wself  = (const float*)d_in[3];
    const float* Wneigh = (const float*)d_in[4];
    float*       out    = (float*)d_out;

    // workspace layout
    float* neigh     = (float*)d_ws;                        // NN*D f32 (51.2MB)
    int*   count     = (int*)(neigh + (size_t)NN * D);      // NN
    int*   offs      = count + NN;                          // NN
    int*   cursor    = offs + NN;                           // NN
    int*   tile_sums = cursor + NN;                         // 128
    int*   tile_base = tile_sums + 128;                     // 128
    int*   eidx      = tile_base + 128;                     // NE (6.4MB)

    hipMemsetAsync(count, 0, NN * sizeof(int), stream);

    k_count<<<dim3((NE + 255) / 256), 256, 0, stream>>>(dst, count);
    k_scan1<<<dim3(N_TILES), 256, 0, stream>>>(count, offs, tile_sums);
    k_scan2<<<dim3(1), 128, 0, stream>>>(tile_sums, tile_base);
    k_scan3<<<dim3((NN + 255) / 256), 256, 0, stream>>>(offs, tile_base, cursor);
    k_fill<<<dim3((NE + 255) / 256), 256, 0, stream>>>(src, dst, cursor, eidx);
    k_pull<<<dim3((NN + 7) / 8), 256, 0, stream>>>(h, offs, count, eidx, neigh);
    sage_gemm<<<dim3(NN / 32), 256, 0, stream>>>(h, neigh, Wself, Wneigh, out);
}

// Round 3
// 381.887 us; speedup vs baseline: 7.8652x; 1.3580x over previous
//
#include <hip/hip_runtime.h>

// SAGEConv mean aggregator — bf16 MFMA version.
// R2 post-mortem: fp32 vector GEMM was 140us (VALUBusy 50%, MfmaUtil 0).
// R3: convert h->bf16 once; pull gathers 256B bf16 rows (halves gather
// traffic); GEMM uses v_mfma_f32_16x16x32_bf16 with W pre-packed into
// B-fragment order and staged in 32KB LDS; A-frags global->register.
// Phases: cvt_h, cvt_w, count, scan, fill, pull(mean,bf16), mfma-gemm.

constexpr int NN = 100000;
constexpr int NE = 1600000;
constexpr int D  = 128;
constexpr int TILE = 1024;                      // scan tile (256 thr x 4)
constexpr int N_TILES = (NN + TILE - 1) / TILE; // 98

typedef __attribute__((ext_vector_type(8))) short short8;   // 8 bf16 (4 VGPR)
typedef __attribute__((ext_vector_type(4))) float floatx4;  // MFMA C/D

static __device__ __forceinline__ unsigned short f2bf(float f) {
    // round-to-nearest-even fp32 -> bf16
    unsigned u = __float_as_uint(f);
    unsigned r = ((u >> 16) & 1u) + 0x7fffu;
    return (unsigned short)((u + r) >> 16);
}
static __device__ __forceinline__ float bflo(unsigned u) { return __uint_as_float(u << 16); }
static __device__ __forceinline__ float bfhi(unsigned u) { return __uint_as_float(u & 0xffff0000u); }

// ---------------------------------------------------------------------------
// h (fp32, NN x 128) -> hb (bf16). 8 elems/thread, 16B stores.
// ---------------------------------------------------------------------------
__global__ __launch_bounds__(256) void k_cvt_h(
    const float* __restrict__ h, unsigned short* __restrict__ hb)
{
    int i = blockIdx.x * 256 + threadIdx.x;          // 1.6M threads, exact
    const float4* h4 = (const float4*)h;
    float4 a = h4[(size_t)i * 2];
    float4 b = h4[(size_t)i * 2 + 1];
    uint4 o;
    o.x = (unsigned)f2bf(a.x) | ((unsigned)f2bf(a.y) << 16);
    o.y = (unsigned)f2bf(a.z) | ((unsigned)f2bf(a.w) << 16);
    o.z = (unsigned)f2bf(b.x) | ((unsigned)f2bf(b.y) << 16);
    o.w = (unsigned)f2bf(b.z) | ((unsigned)f2bf(b.w) << 16);
    ((uint4*)hb)[i] = o;
}

// ---------------------------------------------------------------------------
// Pack Wcat = [W_self ; W_neigh] (256 x 128 fp32) into B-fragment order:
// Wp[kg][col][j] = bf16(Wcat[kg*8+j][col]),  kg in [0,32), j in [0,8).
// Lane reading Wp unit (kg*128+col) gets its 8 contiguous K elems -> b128.
// ---------------------------------------------------------------------------
__global__ __launch_bounds__(128) void k_cvt_w(
    const float* __restrict__ Wself, const float* __restrict__ Wneigh,
    unsigned short* __restrict__ Wp)
{
    int kg  = blockIdx.x;        // 0..31
    int col = threadIdx.x;       // 0..127
    unsigned short v[8];
#pragma unroll
    for (int j = 0; j < 8; ++j) {
        int k = kg * 8 + j;
        const float* W = (k < 128) ? (Wself + (size_t)k * D)
                                   : (Wneigh + (size_t)(k - 128) * D);
        v[j] = f2bf(W[col]);
    }
    uint4 o;
    o.x = (unsigned)v[0] | ((unsigned)v[1] << 16);
    o.y = (unsigned)v[2] | ((unsigned)v[3] << 16);
    o.z = (unsigned)v[4] | ((unsigned)v[5] << 16);
    o.w = (unsigned)v[6] | ((unsigned)v[7] << 16);
    ((uint4*)Wp)[kg * 128 + col] = o;
}

// ---------------------------------------------------------------------------
// CSR build: histogram -> exclusive scan -> cursor fill.
// ---------------------------------------------------------------------------
__global__ __launch_bounds__(256) void k_count(
    const int* __restrict__ dst, int* __restrict__ count)
{
    int e = blockIdx.x * 256 + threadIdx.x;
    if (e < NE) atomicAdd(&count[dst[e]], 1);
}

__global__ __launch_bounds__(256) void k_scan1(
    const int* __restrict__ count, int* __restrict__ cursor,
    int* __restrict__ tile_sums)
{
    __shared__ int sdata[256];
    const int t = threadIdx.x, tile = blockIdx.x;
    const int base = tile * TILE + t * 4;
    int c[4];
#pragma unroll
    for (int j = 0; j < 4; ++j)
        c[j] = (base + j < NN) ? count[base + j] : 0;
    int local = c[0] + c[1] + c[2] + c[3];
    sdata[t] = local;
    __syncthreads();
    for (int off = 1; off < 256; off <<= 1) {
        int v = (t >= off) ? sdata[t - off] : 0;
        __syncthreads();
        sdata[t] += v;
        __syncthreads();
    }
    int run = sdata[t] - local;
#pragma unroll
    for (int j = 0; j < 4; ++j) {
        if (base + j < NN) cursor[base + j] = run;
        run += c[j];
    }
    if (t == 255) tile_sums[tile] = sdata[255];
}

__global__ __launch_bounds__(128) void k_scan2(
    const int* __restrict__ tile_sums, int* __restrict__ tile_base)
{
    __shared__ int sdata[128];
    int t = threadIdx.x;
    int v = (t < N_TILES) ? tile_sums[t] : 0;
    sdata[t] = v;
    __syncthreads();
    for (int off = 1; off < 128; off <<= 1) {
        int x = (t >= off) ? sdata[t - off] : 0;
        __syncthreads();
        sdata[t] += x;
        __syncthreads();
    }
    if (t < N_TILES) tile_base[t] = sdata[t] - v;
}

__global__ __launch_bounds__(256) void k_scan3(
    int* __restrict__ cursor, const int* __restrict__ tile_base)
{
    int i = blockIdx.x * 256 + threadIdx.x;
    if (i < NN) cursor[i] += tile_base[i / TILE];
}

__global__ __launch_bounds__(256) void k_fill(
    const int* __restrict__ src, const int* __restrict__ dst,
    int* __restrict__ cursor, int* __restrict__ eidx)
{
    int e = blockIdx.x * 256 + threadIdx.x;
    if (e < NE) {
        int pos = atomicAdd(&cursor[dst[e]], 1);
        eidx[pos] = src[e];
    }
}

// ---------------------------------------------------------------------------
// Pull mean aggregation over bf16 rows. 16 lanes/node, lane owns one uint4
// (8 bf16 cols) -> each edge is one coalesced 256B row read. After k_fill,
// cursor[v] == row_end, so beg = cursor[v] - count[v] (no offs array).
// Output mean in bf16.
// ---------------------------------------------------------------------------
__global__ __launch_bounds__(256) void k_pull(
    const unsigned short* __restrict__ hb, const int* __restrict__ cursor,
    const int* __restrict__ count, const int* __restrict__ eidx,
    unsigned short* __restrict__ nb)
{
    const int lane = threadIdx.x & 15;
    const int v = blockIdx.x * 16 + (threadIdx.x >> 4);   // NN/16 exact
    const int deg = count[v];
    const int end = cursor[v];
    const int beg = end - deg;
    const uint4* __restrict__ h4 = (const uint4*)hb;      // 16 units per row

    float a0[8] = {0,0,0,0,0,0,0,0};
    float a1[8] = {0,0,0,0,0,0,0,0};
    int e = beg;
    for (; e + 1 < end; e += 2) {
        uint4 x = h4[(size_t)eidx[e]     * 16 + lane];
        uint4 y = h4[(size_t)eidx[e + 1] * 16 + lane];
        a0[0] += bflo(x.x); a0[1] += bfhi(x.x);
        a0[2] += bflo(x.y); a0[3] += bfhi(x.y);
        a0[4] += bflo(x.z); a0[5] += bfhi(x.z);
        a0[6] += bflo(x.w); a0[7] += bfhi(x.w);
        a1[0] += bflo(y.x); a1[1] += bfhi(y.x);
        a1[2] += bflo(y.y); a1[3] += bfhi(y.y);
        a1[4] += bflo(y.z); a1[5] += bfhi(y.z);
        a1[6] += bflo(y.w); a1[7] += bfhi(y.w);
    }
    if (e < end) {
        uint4 x = h4[(size_t)eidx[e] * 16 + lane];
        a0[0] += bflo(x.x); a0[1] += bfhi(x.x);
        a0[2] += bflo(x.y); a0[3] += bfhi(x.y);
        a0[4] += bflo(x.z); a0[5] += bfhi(x.z);
        a0[6] += bflo(x.w); a0[7] += bfhi(x.w);
    }
    float inv = (deg > 0) ? 1.0f / (float)deg : 0.0f;
    uint4 o;
    o.x = (unsigned)f2bf((a0[0]+a1[0])*inv) | ((unsigned)f2bf((a0[1]+a1[1])*inv) << 16);
    o.y = (unsigned)f2bf((a0[2]+a1[2])*inv) | ((unsigned)f2bf((a0[3]+a1[3])*inv) << 16);
    o.z = (unsigned)f2bf((a0[4]+a1[4])*inv) | ((unsigned)f2bf((a0[5]+a1[5])*inv) << 16);
    o.w = (unsigned)f2bf((a0[6]+a1[6])*inv) | ((unsigned)f2bf((a0[7]+a1[7])*inv) << 16);
    ((uint4*)nb)[(size_t)v * 16 + lane] = o;
}

// ---------------------------------------------------------------------------
// out = [hb | nb] @ Wcat via v_mfma_f32_16x16x32_bf16.
// Block: 256 thr = 4 waves; tile 128 nodes x 128 cols, K=256 (2 halves:
// half 0 reads hb, half 1 reads nb). Wave handles 32 rows (2 row-tiles).
// W half (128 K x 128 cols) staged in 32KB LDS in B-frag order: lane reads
// unit (ksL*4 + lane>>4)*128 + col -> 16 consecutive 16B units per 16-lane
// group = all 32 banks evenly, conflict-free. A-frags: direct global b128
// (each X row read exactly once per block -> no LDS, no extra barrier).
// ---------------------------------------------------------------------------
__global__ __launch_bounds__(256) void k_gemm(
    const unsigned short* __restrict__ hb, const unsigned short* __restrict__ nb,
    const unsigned short* __restrict__ Wp, float* __restrict__ out)
{
    __shared__ unsigned short Wl[128 * 128];   // 32 KiB

    const int t    = threadIdx.x;
    const int wave = t >> 6;
    const int lane = t & 63;
    const int l16  = lane & 15;
    const int kg4  = lane >> 4;          // 0..3
    const int v0   = blockIdx.x * 128;

    floatx4 acc[2][8];
#pragma unroll
    for (int rt = 0; rt < 2; ++rt)
#pragma unroll
        for (int ct = 0; ct < 8; ++ct)
            acc[rt][ct] = (floatx4){0.f, 0.f, 0.f, 0.f};

    int rowg[2];
#pragma unroll
    for (int rt = 0; rt < 2; ++rt) {
        int row = v0 + wave * 32 + rt * 16 + l16;
        rowg[rt] = (row < NN) ? row : (NN - 1);   // clamp; stores guarded
    }

    for (int half = 0; half < 2; ++half) {
        __syncthreads();   // previous half's Wl readers done
#pragma unroll
        for (int i = 0; i < 8; ++i) {
            int u = t + i * 256;                       // 0..2047 units (16B)
            ((uint4*)Wl)[u] = ((const uint4*)Wp)[half * 2048 + u];
        }
        __syncthreads();

        const unsigned short* __restrict__ Xsrc = (half == 0) ? hb : nb;
#pragma unroll
        for (int ks = 0; ks < 4; ++ks) {
            short8 a[2];
#pragma unroll
            for (int rt = 0; rt < 2; ++rt)
                a[rt] = *(const short8*)(Xsrc + (size_t)rowg[rt] * D + ks * 32 + kg4 * 8);
#pragma unroll
            for (int ct = 0; ct < 8; ++ct) {
                const short8 b = *(const short8*)(Wl + (((ks * 4 + kg4) * 128) + ct * 16 + l16) * 8);
                acc[0][ct] = __builtin_amdgcn_mfma_f32_16x16x32_bf16(a[0], b, acc[0][ct], 0, 0, 0);
                acc[1][ct] = __builtin_amdgcn_mfma_f32_16x16x32_bf16(a[1], b, acc[1][ct], 0, 0, 0);
            }
        }
    }

    // C/D layout: col = lane&15, row = (lane>>4)*4 + reg   [m89-verified]
#pragma unroll
    for (int rt = 0; rt < 2; ++rt) {
        int rbase = v0 + wave * 32 + rt * 16 + kg4 * 4;
#pragma unroll
        for (int r = 0; r < 4; ++r) {
            int row = rbase + r;
            if (row < NN) {
                float* o = out + (size_t)row * D + l16;
#pragma unroll
                for (int ct = 0; ct < 8; ++ct)
                    o[ct * 16] = acc[rt][ct][r];
            }
        }
    }
}

extern "C" void kernel_launch(void* const* d_in, const int* in_sizes, int n_in,
                              void* d_out, int out_size, void* d_ws, size_t ws_size,
                              hipStream_t stream) {
    const float* h      = (const float*)d_in[0];
    const int*   src    = (const int*)d_in[1];
    const int*   dst    = (const int*)d_in[2];
    const float* Wself  = (const float*)d_in[3];
    const float* Wneigh = (const float*)d_in[4];
    float*       out    = (float*)d_out;

    // workspace layout (16B-aligned chunks first), ~58.5 MB total
    unsigned short* hb = (unsigned short*)d_ws;            // NN*D bf16 (25.6MB)
    unsigned short* nb = hb + (size_t)NN * D;              // NN*D bf16 (25.6MB)
    unsigned short* Wp = nb + (size_t)NN * D;              // 256*128 bf16 (64KB)
    int* eidx      = (int*)(Wp + 256 * D);                 // NE (6.4MB)
    int* count     = eidx + NE;                            // NN
    int* cursor    = count + NN;                           // NN
    int* tile_sums = cursor + NN;                          // 128
    int* tile_base = tile_sums + 128;                      // 128

    hipMemsetAsync(count, 0, NN * sizeof(int), stream);

    k_cvt_h<<<dim3(NN * D / 8 / 256), 256, 0, stream>>>(h, hb);
    k_cvt_w<<<dim3(32), 128, 0, stream>>>(Wself, Wneigh, Wp);
    k_count<<<dim3((NE + 255) / 256), 256, 0, stream>>>(dst, count);
    k_scan1<<<dim3(N_TILES), 256, 0, stream>>>(count, cursor, tile_sums);
    k_scan2<<<dim3(1), 128, 0, stream>>>(tile_sums, tile_base);
    k_scan3<<<dim3((NN + 255) / 256), 256, 0, stream>>>(cursor, tile_base);
    k_fill<<<dim3((NE + 255) / 256), 256, 0, stream>>>(src, dst, cursor, eidx);
    k_pull<<<dim3(NN / 16), 256, 0, stream>>>(hb, cursor, count, eidx, nb);
    k_gemm<<<dim3((NN + 127) / 128), 256, 0, stream>>>(hb, nb, Wp, out);
}